// Round 1
// baseline (6206.218 us; speedup 1.0000x reference)
//
#include <hip/hip_runtime.h>
#include <hip/hip_bf16.h>
#include <cmath>

// ---------------------------------------------------------------------------
// GQA forward, fp32 baseline (correctness-first; no MFMA yet).
// B=4, T=2048, D_MODEL=2048, N_Q=32, N_KV=8, HEAD=64, N_REP=4.
//
// Pipeline:
//   1. rope_tables_k : sin/cos[T][32]
//   2. gemm_f32_k x3 : qkv_raw[8192][3072] = x @ [Wq | Wk | Wv]
//   3. rope_apply_k  : in-place interleaved RoPE on q cols [0,2048) and k cols [2048,2560)
//   4. attn_k        : causal GQA flash attention -> ctx[8192][2048]
//   5. gemm_f32_k    : out = ctx @ Wo
//
// ws layout (floats): qkv_raw 25165824 | ctx 16777216 | sin 65536 | cos 65536
// total = 42,074,112 floats = 168.3 MB
// ---------------------------------------------------------------------------

#define T_SEQ 2048
#define BATCH 4
#define DMODEL 2048
#define NQ 32
#define NKV 8
#define HEADD 64

// --------------------------- RoPE tables -----------------------------------
__global__ void rope_tables_k(float* __restrict__ sin_t, float* __restrict__ cos_t) {
    int idx = blockIdx.x * blockDim.x + threadIdx.x;   // 0 .. T*32-1
    if (idx >= T_SEQ * 32) return;
    int t = idx >> 5;
    int i = idx & 31;
    // inv_freq = 10000^(-2i/64), computed like jax (fp32 pow via exp2)
    float inv_freq = exp2f(((float)(-2 * i) / 64.0f) * 13.287712379549449f); // log2(10000)
    float ang = (float)t * inv_freq;
    sin_t[idx] = sinf(ang);
    cos_t[idx] = cosf(ang);
}

// --------------------------- fp32 GEMM -------------------------------------
// C[row][coff + n0 + ...] = A (M,K) @ B (K,N); C leading dim = ldc.
// 128x128 tile, BK=16, 256 threads, 8x8 micro-tile (split 4+4 for coalescing).
__global__ __launch_bounds__(256) void gemm_f32_k(
    const float* __restrict__ A, const float* __restrict__ B, float* __restrict__ C,
    int M, int N, int K, int ldc, int coff)
{
    constexpr int BM = 128, BN = 128, BK = 16;
    __shared__ float As[BK][BM + 4];   // k-major (transposed on store)
    __shared__ float Bs[BK][BN + 4];

    const int tid = threadIdx.x;
    const int n0 = blockIdx.x * BN;
    const int m0 = blockIdx.y * BM;
    const int tx = tid & 15;
    const int ty = tid >> 4;

    float acc[8][8];
#pragma unroll
    for (int i = 0; i < 8; i++)
#pragma unroll
        for (int j = 0; j < 8; j++) acc[i][j] = 0.0f;

    for (int k0 = 0; k0 < K; k0 += BK) {
        __syncthreads();
#pragma unroll
        for (int i = 0; i < 2; i++) {
            int flat = tid + i * 256;            // 0..511
            // A tile: 128 rows x 4 float4
            int r  = flat >> 2, c4 = flat & 3;
            float4 av = *(const float4*)&A[(size_t)(m0 + r) * K + k0 + c4 * 4];
            As[c4 * 4 + 0][r] = av.x;
            As[c4 * 4 + 1][r] = av.y;
            As[c4 * 4 + 2][r] = av.z;
            As[c4 * 4 + 3][r] = av.w;
            // B tile: 16 rows x 32 float4 (fully coalesced)
            int rb = flat >> 5, cb = flat & 31;
            float4 bv = *(const float4*)&B[(size_t)(k0 + rb) * N + n0 + cb * 4];
            *(float4*)&Bs[rb][cb * 4] = bv;
        }
        __syncthreads();
#pragma unroll
        for (int k = 0; k < BK; k++) {
            float4 a0 = *(const float4*)&As[k][ty * 4];
            float4 a1 = *(const float4*)&As[k][64 + ty * 4];
            float4 b0 = *(const float4*)&Bs[k][tx * 4];
            float4 b1 = *(const float4*)&Bs[k][64 + tx * 4];
            float ar[8] = {a0.x, a0.y, a0.z, a0.w, a1.x, a1.y, a1.z, a1.w};
            float br[8] = {b0.x, b0.y, b0.z, b0.w, b1.x, b1.y, b1.z, b1.w};
#pragma unroll
            for (int i = 0; i < 8; i++)
#pragma unroll
                for (int j = 0; j < 8; j++)
                    acc[i][j] = fmaf(ar[i], br[j], acc[i][j]);
        }
    }

#pragma unroll
    for (int i = 0; i < 8; i++) {
        int row = m0 + (i >> 2) * 64 + ty * 4 + (i & 3);
        float* crow = C + (size_t)row * ldc + coff + n0;
        *(float4*)&crow[tx * 4]      = make_float4(acc[i][0], acc[i][1], acc[i][2], acc[i][3]);
        *(float4*)&crow[64 + tx * 4] = make_float4(acc[i][4], acc[i][5], acc[i][6], acc[i][7]);
    }
}

// --------------------------- RoPE apply (in place) -------------------------
// qkv_raw rows (b*T + t), 3072 cols: q = [0,2048), k = [2048,2560), v untouched.
__global__ void rope_apply_k(float* __restrict__ qkv,
                             const float* __restrict__ sin_t,
                             const float* __restrict__ cos_t)
{
    const int total = BATCH * T_SEQ * (NQ + NKV) * 32;   // pairs
    int idx = blockIdx.x * blockDim.x + threadIdx.x;
    if (idx >= total) return;
    int row = idx / ((NQ + NKV) * 32);       // b*T + t
    int pr  = idx % ((NQ + NKV) * 32);
    int hh  = pr >> 5;                        // 0..39 (0..31 q heads, 32..39 k heads)
    int pi  = pr & 31;                        // pair index within head
    int t   = row & (T_SEQ - 1);
    int col = (hh < NQ) ? (hh * HEADD + 2 * pi)
                        : (DMODEL + (hh - NQ) * HEADD + 2 * pi);
    size_t base = (size_t)row * 3072 + col;
    float2 eo = *(float2*)&qkv[base];
    float s = sin_t[t * 32 + pi];
    float c = cos_t[t * 32 + pi];
    float2 r;
    r.x = eo.x * c - eo.y * s;
    r.y = eo.x * s + eo.y * c;
    *(float2*)&qkv[base] = r;
}

// --------------------------- causal GQA attention --------------------------
// One block = (b, h, 256-query tile); one query per lane; flash online softmax
// fully per-lane (each lane owns a whole row -> no cross-lane reduce).
// K/V tiles (64 x 64 fp32) staged in LDS with +4 pad; compute reads are
// wave-uniform (broadcast, conflict-free).
__global__ __launch_bounds__(256) void attn_k(const float* __restrict__ qkv,
                                              float* __restrict__ ctx)
{
    constexpr int QT = 256, KT = 64;
    const int blk = blockIdx.x;
    const int qt = blk & 7;            // T/QT = 8
    const int h  = (blk >> 3) & 31;
    const int b  = blk >> 8;
    const int g  = h >> 2;             // kv head
    const int tid = threadIdx.x;
    const int t = qt * QT + tid;       // this lane's query row

    __shared__ float Ks[KT][68];
    __shared__ float Vs[KT][68];

    float q[64], o[64];
    const float* qrow = qkv + (size_t)(b * T_SEQ + t) * 3072 + h * HEADD;
#pragma unroll
    for (int d4 = 0; d4 < 16; d4++) {
        float4 v = *(const float4*)&qrow[d4 * 4];
        q[d4 * 4 + 0] = v.x; q[d4 * 4 + 1] = v.y;
        q[d4 * 4 + 2] = v.z; q[d4 * 4 + 3] = v.w;
    }
#pragma unroll
    for (int d = 0; d < 64; d++) o[d] = 0.0f;

    float m = -1e30f, l = 0.0f;
    const float scale = 0.125f;        // 1/sqrt(64)
    const int kend = (qt + 1) * QT;    // keys needed by the largest t in block

    for (int k0 = 0; k0 < kend; k0 += KT) {
        __syncthreads();
        // stage K,V tile: 64 rows x 16 float4 each
#pragma unroll
        for (int rep = 0; rep < 4; rep++) {
            int flat = rep * 256 + tid;          // 0..1023
            int r  = flat >> 4;
            int c4 = flat & 15;
            size_t grow = (size_t)(b * T_SEQ + k0 + r) * 3072;
            *(float4*)&Ks[r][c4 * 4] = *(const float4*)&qkv[grow + DMODEL + g * HEADD + c4 * 4];
            *(float4*)&Vs[r][c4 * 4] = *(const float4*)&qkv[grow + DMODEL + 512 + g * HEADD + c4 * 4];
        }
        __syncthreads();

#pragma unroll 1
        for (int sub = 0; sub < 4; sub++) {
            const int jb = sub * 16;
            float s[16];
            // scores: s[j] = q . K[jb+j]   (4 partial chains to avoid latency stall)
#pragma unroll
            for (int j = 0; j < 16; j++) {
                float s0 = 0.f, s1 = 0.f, s2 = 0.f, s3 = 0.f;
#pragma unroll
                for (int d4 = 0; d4 < 16; d4++) {
                    float4 kv = *(const float4*)&Ks[jb + j][d4 * 4];
                    s0 = fmaf(q[d4 * 4 + 0], kv.x, s0);
                    s1 = fmaf(q[d4 * 4 + 1], kv.y, s1);
                    s2 = fmaf(q[d4 * 4 + 2], kv.z, s2);
                    s3 = fmaf(q[d4 * 4 + 3], kv.w, s3);
                }
                s[j] = (s0 + s1) + (s2 + s3);
            }
            // online softmax update (per-lane, independent)
            float mt = m;
#pragma unroll
            for (int j = 0; j < 16; j++) {
                int kk = k0 + jb + j;
                s[j] = (kk <= t) ? s[j] * scale : -1e30f;
                mt = fmaxf(mt, s[j]);
            }
            float sc = __expf(m - mt);
            l *= sc;
#pragma unroll
            for (int d = 0; d < 64; d++) o[d] *= sc;
#pragma unroll
            for (int j = 0; j < 16; j++) {
                float p = __expf(s[j] - mt);
                l += p;
                s[j] = p;
            }
            m = mt;
            // o += P @ V
#pragma unroll
            for (int j = 0; j < 16; j++) {
                float pj = s[j];
#pragma unroll
                for (int d4 = 0; d4 < 16; d4++) {
                    float4 vv = *(const float4*)&Vs[jb + j][d4 * 4];
                    o[d4 * 4 + 0] = fmaf(pj, vv.x, o[d4 * 4 + 0]);
                    o[d4 * 4 + 1] = fmaf(pj, vv.y, o[d4 * 4 + 1]);
                    o[d4 * 4 + 2] = fmaf(pj, vv.z, o[d4 * 4 + 2]);
                    o[d4 * 4 + 3] = fmaf(pj, vv.w, o[d4 * 4 + 3]);
                }
            }
        }
    }

    float inv_l = 1.0f / l;
    float* crow = ctx + (size_t)(b * T_SEQ + t) * DMODEL + h * HEADD;
#pragma unroll
    for (int d4 = 0; d4 < 16; d4++) {
        *(float4*)&crow[d4 * 4] = make_float4(o[d4 * 4 + 0] * inv_l, o[d4 * 4 + 1] * inv_l,
                                              o[d4 * 4 + 2] * inv_l, o[d4 * 4 + 3] * inv_l);
    }
}

// --------------------------- launch ----------------------------------------
extern "C" void kernel_launch(void* const* d_in, const int* in_sizes, int n_in,
                              void* d_out, int out_size, void* d_ws, size_t ws_size,
                              hipStream_t stream)
{
    const float* x  = (const float*)d_in[0];
    const float* Wq = (const float*)d_in[1];
    const float* Wk = (const float*)d_in[2];
    const float* Wv = (const float*)d_in[3];
    const float* Wo = (const float*)d_in[4];
    float* out = (float*)d_out;

    float* ws    = (float*)d_ws;
    float* qkv   = ws;                          // 8192*3072 = 25,165,824
    float* ctx   = ws + 25165824;               // 8192*2048 = 16,777,216
    float* sin_t = ws + 25165824 + 16777216;    // 65536
    float* cos_t = sin_t + 65536;               // 65536

    dim3 blk(256);

    rope_tables_k<<<dim3(256), blk, 0, stream>>>(sin_t, cos_t);

    // qkv projections (M=8192, K=2048), packed into qkv_raw (ldc=3072)
    gemm_f32_k<<<dim3(16, 64), blk, 0, stream>>>(x, Wq, qkv, 8192, 2048, 2048, 3072, 0);
    gemm_f32_k<<<dim3(4, 64),  blk, 0, stream>>>(x, Wk, qkv, 8192, 512,  2048, 3072, 2048);
    gemm_f32_k<<<dim3(4, 64),  blk, 0, stream>>>(x, Wv, qkv, 8192, 512,  2048, 3072, 2560);

    // RoPE on q and k, in place
    rope_apply_k<<<dim3((BATCH * T_SEQ * (NQ + NKV) * 32 + 255) / 256), blk, 0, stream>>>(
        qkv, sin_t, cos_t);

    // causal GQA attention -> ctx
    attn_k<<<dim3(BATCH * NQ * (T_SEQ / 256)), blk, 0, stream>>>(qkv, ctx);

    // output projection
    gemm_f32_k<<<dim3(16, 64), blk, 0, stream>>>(ctx, Wo, out, 8192, 2048, 2048, 2048, 0);
}

// Round 9
// 4299.068 us; speedup vs baseline: 1.4436x; 1.4436x over previous
//
#include <hip/hip_runtime.h>
#include <hip/hip_bf16.h>
#include <cmath>

// ---------------------------------------------------------------------------
// GQA forward — BISECTION ROUND: bf16 MFMA GEMMs + round-1's verified scalar
// attention (ported to bf16 I/O).  Isolates {MFMA attn core} vs {bf16 GEMM
// pipeline} as the source of the shared absmax-0.377 failure.
//
//  1. rope_tables_k : sin/cos[T][32] fp32
//  2. cast_x_k      : x fp32 -> bf16
//  3. wtrans_k x4   : W fp32 [K][N] -> Wt bf16 [N][K]
//  4. gemm_k<1>     : qkv_bf[8192][3072] = x_bf @ [Wq|Wk|Wv]   (bf16 out)
//  5. rope_apply_k  : in-place RoPE on q cols [0,2048), k cols [2048,2560)
//  6. attn_scalar_k : round-1 verified scalar flash attention (fp32 math,
//                     bf16 loads/stores) -> ctx_bf
//  7. gemm_k<0>     : out = ctx_bf @ Wo   (fp32 out)
// ---------------------------------------------------------------------------

#define T_SEQ 2048
#define BATCH 4
#define DMODEL 2048
#define NQH 32
#define NKVH 8
#define HD 64

typedef short short8 __attribute__((ext_vector_type(8)));
typedef float f32x4 __attribute__((ext_vector_type(4)));
typedef unsigned short ushort8v __attribute__((ext_vector_type(8)));

__device__ __forceinline__ unsigned short f2bf(float f) {
    unsigned u = __float_as_uint(f);
    u += 0x7FFF + ((u >> 16) & 1);          // RNE
    return (unsigned short)(u >> 16);
}
__device__ __forceinline__ float bf2f(unsigned short b) {
    return __uint_as_float(((unsigned)b) << 16);
}
__device__ __forceinline__ void gload_lds16(const void* g, void* l) {
    __builtin_amdgcn_global_load_lds((const __attribute__((address_space(1))) void*)g,
                                     (__attribute__((address_space(3))) void*)l, 16, 0, 0);
}

// --------------------------- RoPE tables -----------------------------------
__global__ void rope_tables_k(float* __restrict__ sin_t, float* __restrict__ cos_t) {
    int idx = blockIdx.x * blockDim.x + threadIdx.x;
    if (idx >= T_SEQ * 32) return;
    int t = idx >> 5;
    int i = idx & 31;
    float inv_freq = exp2f(((float)(-2 * i) / 64.0f) * 13.287712379549449f); // log2(10000)
    float ang = (float)t * inv_freq;
    sin_t[idx] = sinf(ang);
    cos_t[idx] = cosf(ang);
}

// --------------------------- x cast ----------------------------------------
__global__ void cast_x_k(const float* __restrict__ x, unsigned short* __restrict__ xb, int n8) {
    const int i = blockIdx.x * blockDim.x + threadIdx.x;
    if (i >= n8) return;
    const float4 a = *(const float4*)(x + (size_t)i * 8);
    const float4 b = *(const float4*)(x + (size_t)i * 8 + 4);
    ushort8v o;
    o[0] = f2bf(a.x); o[1] = f2bf(a.y); o[2] = f2bf(a.z); o[3] = f2bf(a.w);
    o[4] = f2bf(b.x); o[5] = f2bf(b.y); o[6] = f2bf(b.z); o[7] = f2bf(b.w);
    *(ushort8v*)(xb + (size_t)i * 8) = o;
}

// --------------------------- weight transpose+cast -------------------------
__global__ __launch_bounds__(256) void wtrans_k(const float* __restrict__ W,
                                                unsigned short* __restrict__ Wt,
                                                int Kd, int Nw, int roff) {
    __shared__ float tile[32][33];
    const int n0 = blockIdx.x * 32, k0 = blockIdx.y * 32;
    const int tx = threadIdx.x & 31, ty = threadIdx.x >> 5;
#pragma unroll
    for (int i = 0; i < 4; i++) {
        int r = ty + i * 8;
        tile[r][tx] = W[(size_t)(k0 + r) * Nw + n0 + tx];
    }
    __syncthreads();
#pragma unroll
    for (int i = 0; i < 4; i++) {
        int r = ty + i * 8;
        Wt[(size_t)(roff + n0 + r) * Kd + k0 + tx] = f2bf(tile[tx][r]);
    }
}

// --------------------------- bf16 MFMA GEMM --------------------------------
template <int BF16OUT>
__global__ __launch_bounds__(256) void gemm_k(const unsigned short* __restrict__ A,
                                              const unsigned short* __restrict__ Bt,
                                              void* __restrict__ Cv,
                                              int M, int N, int K) {
    __shared__ __align__(16) unsigned short Al[128 * 32];
    __shared__ __align__(16) unsigned short Bl[128 * 32];
    const int tid = threadIdx.x;
    const int lane = tid & 63, wid = tid >> 6;
    const int wm = wid >> 1, wn = wid & 1;
    const int l15 = lane & 15, lg = lane >> 4;
    const size_t m0 = (size_t)blockIdx.y * 128, n0 = (size_t)blockIdx.x * 128;

    f32x4 acc[4][4];
#pragma unroll
    for (int m = 0; m < 4; m++)
#pragma unroll
        for (int n = 0; n < 4; n++)
#pragma unroll
            for (int r = 0; r < 4; r++) acc[m][n][r] = 0.f;

    for (int k0 = 0; k0 < K; k0 += 32) {
        __syncthreads();
#pragma unroll
        for (int p = 0; p < 2; p++) {
            const int u = tid + p * 256;
            const int r = u >> 2, c = u & 3;
            const int cl = c ^ ((r >> 2) & 3);
            gload_lds16(A + (m0 + r) * (size_t)K + k0 + cl * 8,
                        (char*)Al + (wid * 64 + p * 256) * 16);
            gload_lds16(Bt + (n0 + r) * (size_t)K + k0 + cl * 8,
                        (char*)Bl + (wid * 64 + p * 256) * 16);
        }
        __syncthreads();
        short8 af[4], bf[4];
#pragma unroll
        for (int m = 0; m < 4; m++) {
            const int row = wm * 64 + m * 16 + l15;
            const int cph = lg ^ ((row >> 2) & 3);
            af[m] = *(const short8*)&Al[row * 32 + cph * 8];
        }
#pragma unroll
        for (int n = 0; n < 4; n++) {
            const int row = wn * 64 + n * 16 + l15;
            const int cph = lg ^ ((row >> 2) & 3);
            bf[n] = *(const short8*)&Bl[row * 32 + cph * 8];
        }
#pragma unroll
        for (int m = 0; m < 4; m++)
#pragma unroll
            for (int n = 0; n < 4; n++)
                acc[m][n] = __builtin_amdgcn_mfma_f32_16x16x32_bf16(af[m], bf[n], acc[m][n], 0, 0, 0);
    }
#pragma unroll
    for (int m = 0; m < 4; m++) {
#pragma unroll
        for (int r = 0; r < 4; r++) {
            const size_t row = m0 + wm * 64 + m * 16 + lg * 4 + r;
#pragma unroll
            for (int n = 0; n < 4; n++) {
                const size_t col = n0 + wn * 64 + n * 16 + l15;
                if (BF16OUT)
                    ((unsigned short*)Cv)[row * N + col] = f2bf(acc[m][n][r]);
                else
                    ((float*)Cv)[row * N + col] = acc[m][n][r];
            }
        }
    }
}

// --------------------------- RoPE apply (bf16, in place) -------------------
__global__ void rope_apply_k(unsigned short* __restrict__ qkv,
                             const float* __restrict__ sin_t,
                             const float* __restrict__ cos_t) {
    const int idx = blockIdx.x * blockDim.x + threadIdx.x;
    const int total = BATCH * T_SEQ * 40 * 8;
    if (idx >= total) return;
    const int row = idx / 320;
    const int rem = idx - row * 320;
    const int hh = rem >> 3, pq = rem & 7;
    const int t = row & (T_SEQ - 1);
    const int col = (hh < NQH ? hh * HD : DMODEL + (hh - NQH) * HD) + pq * 8;
    unsigned short* p = qkv + (size_t)row * 3072 + col;
    ushort8v v = *(const ushort8v*)p;
    const float4 sv = *(const float4*)&sin_t[t * 32 + pq * 4];
    const float4 cv = *(const float4*)&cos_t[t * 32 + pq * 4];
    const float s[4] = {sv.x, sv.y, sv.z, sv.w};
    const float c[4] = {cv.x, cv.y, cv.z, cv.w};
#pragma unroll
    for (int j = 0; j < 4; j++) {
        const float e = bf2f(v[2 * j]), o = bf2f(v[2 * j + 1]);
        v[2 * j]     = f2bf(e * c[j] - o * s[j]);
        v[2 * j + 1] = f2bf(e * s[j] + o * c[j]);
    }
    *(ushort8v*)p = v;
}

// --------------------------- scalar attention (round-1 verified) -----------
// One block = (b, h, 256-query tile); one query per lane; flash online softmax
// fully per-lane.  Inner compute loops identical to round 1 (which PASSED);
// only the global loads/stores are bf16<->fp32 converted.
__global__ __launch_bounds__(256) void attn_scalar_k(const unsigned short* __restrict__ qkv,
                                                     unsigned short* __restrict__ ctx)
{
    constexpr int QT = 256, KT = 64;
    const int blk = blockIdx.x;
    const int qt = blk & 7;            // T/QT = 8
    const int h  = (blk >> 3) & 31;
    const int b  = blk >> 8;
    const int g  = h >> 2;
    const int tid = threadIdx.x;
    const int t = qt * QT + tid;

    __shared__ float Ks[KT][68];
    __shared__ float Vs[KT][68];

    float q[64], o[64];
    const unsigned short* qrow = qkv + (size_t)(b * T_SEQ + t) * 3072 + h * HD;
#pragma unroll
    for (int d8 = 0; d8 < 8; d8++) {
        ushort8v v = *(const ushort8v*)&qrow[d8 * 8];
#pragma unroll
        for (int j = 0; j < 8; j++) q[d8 * 8 + j] = bf2f(v[j]);
    }
#pragma unroll
    for (int d = 0; d < 64; d++) o[d] = 0.0f;

    float m = -1e30f, l = 0.0f;
    const float scale = 0.125f;        // 1/sqrt(64)
    const int kend = (qt + 1) * QT;

    for (int k0 = 0; k0 < kend; k0 += KT) {
        __syncthreads();
        // stage K,V tile (bf16 -> fp32): 64 rows x 8 chunks of 8
#pragma unroll
        for (int rep = 0; rep < 2; rep++) {
            int flat = rep * 256 + tid;          // 0..511
            int r  = flat >> 3;
            int c8 = flat & 7;
            size_t grow = (size_t)(b * T_SEQ + k0 + r) * 3072;
            ushort8v kv8 = *(const ushort8v*)&qkv[grow + DMODEL + g * HD + c8 * 8];
            ushort8v vv8 = *(const ushort8v*)&qkv[grow + DMODEL + 512 + g * HD + c8 * 8];
#pragma unroll
            for (int j = 0; j < 8; j++) {
                Ks[r][c8 * 8 + j] = bf2f(kv8[j]);
                Vs[r][c8 * 8 + j] = bf2f(vv8[j]);
            }
        }
        __syncthreads();

#pragma unroll 1
        for (int sub = 0; sub < 4; sub++) {
            const int jb = sub * 16;
            float s[16];
#pragma unroll
            for (int j = 0; j < 16; j++) {
                float s0 = 0.f, s1 = 0.f, s2 = 0.f, s3 = 0.f;
#pragma unroll
                for (int d4 = 0; d4 < 16; d4++) {
                    float4 kv = *(const float4*)&Ks[jb + j][d4 * 4];
                    s0 = fmaf(q[d4 * 4 + 0], kv.x, s0);
                    s1 = fmaf(q[d4 * 4 + 1], kv.y, s1);
                    s2 = fmaf(q[d4 * 4 + 2], kv.z, s2);
                    s3 = fmaf(q[d4 * 4 + 3], kv.w, s3);
                }
                s[j] = (s0 + s1) + (s2 + s3);
            }
            float mt = m;
#pragma unroll
            for (int j = 0; j < 16; j++) {
                int kk = k0 + jb + j;
                s[j] = (kk <= t) ? s[j] * scale : -1e30f;
                mt = fmaxf(mt, s[j]);
            }
            float sc = __expf(m - mt);
            l *= sc;
#pragma unroll
            for (int d = 0; d < 64; d++) o[d] *= sc;
#pragma unroll
            for (int j = 0; j < 16; j++) {
                float p = __expf(s[j] - mt);
                l += p;
                s[j] = p;
            }
            m = mt;
#pragma unroll
            for (int j = 0; j < 16; j++) {
                float pj = s[j];
#pragma unroll
                for (int d4 = 0; d4 < 16; d4++) {
                    float4 vv = *(const float4*)&Vs[jb + j][d4 * 4];
                    o[d4 * 4 + 0] = fmaf(pj, vv.x, o[d4 * 4 + 0]);
                    o[d4 * 4 + 1] = fmaf(pj, vv.y, o[d4 * 4 + 1]);
                    o[d4 * 4 + 2] = fmaf(pj, vv.z, o[d4 * 4 + 2]);
                    o[d4 * 4 + 3] = fmaf(pj, vv.w, o[d4 * 4 + 3]);
                }
            }
        }
    }

    const float inv_l = 1.0f / l;
    unsigned short* crow = ctx + (size_t)(b * T_SEQ + t) * DMODEL + h * HD;
#pragma unroll
    for (int d8 = 0; d8 < 8; d8++) {
        ushort8v ov;
#pragma unroll
        for (int j = 0; j < 8; j++) ov[j] = f2bf(o[d8 * 8 + j] * inv_l);
        *(ushort8v*)&crow[d8 * 8] = ov;
    }
}

// --------------------------- launch ----------------------------------------
extern "C" void kernel_launch(void* const* d_in, const int* in_sizes, int n_in,
                              void* d_out, int out_size, void* d_ws, size_t ws_size,
                              hipStream_t stream) {
    const float* x  = (const float*)d_in[0];
    const float* Wq = (const float*)d_in[1];
    const float* Wk = (const float*)d_in[2];
    const float* Wv = (const float*)d_in[3];
    const float* Wo = (const float*)d_in[4];
    float* out = (float*)d_out;

    char* w = (char*)d_ws;
    unsigned short* qkv_bf  = (unsigned short*)(w);              // 50,331,648 B
    unsigned short* ctx_bf  = (unsigned short*)(w + 50331648);   // 33,554,432 B
    unsigned short* x_bf    = (unsigned short*)(w + 83886080);   // 33,554,432 B
    unsigned short* WqkvT   = (unsigned short*)(w + 117440512);  // 12,582,912 B
    unsigned short* WoT     = (unsigned short*)(w + 130023424);  //  8,388,608 B
    float* sin_t = (float*)(w + 155189248);                      //    262,144 B
    float* cos_t = (float*)(w + 155451392);                      //    262,144 B

    dim3 blk(256);

    rope_tables_k<<<dim3(256), blk, 0, stream>>>(sin_t, cos_t);
    cast_x_k<<<dim3(8192), blk, 0, stream>>>(x, x_bf, 2097152);

    wtrans_k<<<dim3(64, 64), blk, 0, stream>>>(Wq, WqkvT, 2048, 2048, 0);
    wtrans_k<<<dim3(16, 64), blk, 0, stream>>>(Wk, WqkvT, 2048, 512, 2048);
    wtrans_k<<<dim3(16, 64), blk, 0, stream>>>(Wv, WqkvT, 2048, 512, 2560);
    wtrans_k<<<dim3(64, 64), blk, 0, stream>>>(Wo, WoT, 2048, 2048, 0);

    // qkv = x @ [Wq|Wk|Wv]   M=8192 N=3072 K=2048, bf16 out
    gemm_k<1><<<dim3(24, 64), blk, 0, stream>>>(x_bf, WqkvT, (void*)qkv_bf, 8192, 3072, 2048);

    rope_apply_k<<<dim3(10240), blk, 0, stream>>>(qkv_bf, sin_t, cos_t);

    // round-1 verified scalar attention (bf16 I/O) -> ctx_bf
    attn_scalar_k<<<dim3(BATCH * NQH * (T_SEQ / 256)), blk, 0, stream>>>(qkv_bf, ctx_bf);

    // out = ctx @ Wo   M=8192 N=2048 K=2048, fp32 out
    gemm_k<0><<<dim3(16, 64), blk, 0, stream>>>(ctx_bf, WoT, (void*)out, 8192, 2048, 2048);
}